// Round 4
// baseline (136.331 us; speedup 1.0000x reference)
//
#include <hip/hip_runtime.h>
#include <hip/hip_bf16.h>

typedef __attribute__((ext_vector_type(4))) float f32x4;
typedef __attribute__((ext_vector_type(8))) short bf16x8;

static __device__ __forceinline__ unsigned int f2bf(float f) {
    unsigned int u = __float_as_uint(f);
    return (u + 0x7FFFu + ((u >> 16) & 1u)) >> 16;   // RNE
}

static __device__ __forceinline__ void gload_lds16(const void* g, void* l) {
    __builtin_amdgcn_global_load_lds(
        (const __attribute__((address_space(1))) unsigned int*)g,
        (__attribute__((address_space(3))) unsigned int*)l, 16, 0, 0);
}

// ---- prep 1: W fragment-ordered wq[p][kh][f][ch] = bf16(exp(k1)-exp(k2)) ----
__global__ __launch_bounds__(256) void wprep_kernel(const float* __restrict__ k1,
                                                    const float* __restrict__ k2,
                                                    unsigned short* __restrict__ wq) {
    int idx = blockIdx.x * 256 + threadIdx.x;          // 9*2*128*32 = 73728
    if (idx >= 73728) return;
    int f  = idx & 127;
    int ch = (idx >> 7) & 31;
    int kh = (idx >> 12) & 1;
    int p  = idx >> 13;
    int src = (p * 64 + kh * 32 + ch) * 128 + f;       // k1/k2 are (p, c, f); f contiguous
    float v = expf(k1[src]) - expf(k2[src]);
    wq[((p * 2 + kh) * 128 + f) * 32 + ch] = (unsigned short)f2bf(v);
}

// ---- prep 2: x NCHW f32 -> PRE-SWIZZLED NHWC bf16 ----
// Row (b,h) = 64 col x 64 c shorts; 16-B granule j within row holds c-block (j&7)^(col&7),
// so conv can stage with LINEAR global_load_lds and read swizzled fragments directly.
__global__ __launch_bounds__(256) void xprep_kernel(const float* __restrict__ x,
                                                    unsigned short* __restrict__ xsw) {
    __shared__ float t[64][65];
    int b = blockIdx.x >> 6;
    int h = blockIdx.x & 63;
    const float* xb = x + b * 262144 + h * 64;         // + c*4096 + col
    int tid = threadIdx.x;
    int col4 = (tid & 15) * 4;
    int c0   = tid >> 4;                               // 0..15
#pragma unroll
    for (int i = 0; i < 4; ++i) {
        int c = c0 + i * 16;
        f32x4 v = *(const f32x4*)(xb + c * 4096 + col4);
        t[c][col4 + 0] = v[0]; t[c][col4 + 1] = v[1];
        t[c][col4 + 2] = v[2]; t[c][col4 + 3] = v[3];
    }
    __syncthreads();
    unsigned short* orow = xsw + ((b * 64 + h) * 64) * 64;
#pragma unroll
    for (int i = 0; i < 2; ++i) {
        int j   = tid + i * 256;                       // granule 0..511
        int col = j >> 3;
        int cb  = ((j & 7) ^ (col & 7)) * 8;           // swizzled c-block
        uint4 pk;
        pk.x = f2bf(t[cb + 0][col]) | (f2bf(t[cb + 1][col]) << 16);
        pk.y = f2bf(t[cb + 2][col]) | (f2bf(t[cb + 3][col]) << 16);
        pk.z = f2bf(t[cb + 4][col]) | (f2bf(t[cb + 5][col]) << 16);
        pk.w = f2bf(t[cb + 6][col]) | (f2bf(t[cb + 7][col]) << 16);
        *(uint4*)(orow + j * 8) = pk;                  // fully coalesced
    }
}

// ---- main: implicit-GEMM conv; stage = linear async global->LDS copy ----
// M = 128 F, N = 128 (2 oh rows x 64 ow-pad), K = 576. Per block: 1 image, 2 output rows.
__global__ __launch_bounds__(256, 2) void conv_kernel(const unsigned short* __restrict__ xsw,
                                                      const unsigned short* __restrict__ wq,
                                                      const float* __restrict__ bias,
                                                      float* __restrict__ out) {
    __shared__ unsigned short xs[4 * 64 * 64];   // 32768 B, already-swizzled image rows

    int bid0 = blockIdx.x;                       // 992 = 8 * 124
    int bid  = (bid0 & 7) * 124 + (bid0 >> 3);   // XCD-chunked swizzle (bijective)
    int b    = bid / 31;
    int tile = bid - b * 31;
    int oh0  = tile * 2;                         // output rows oh0, oh0+1; x rows oh0..oh0+3

    int tid  = threadIdx.x;
    int lane = tid & 63;
    int wid  = tid >> 6;
    int wr   = wid >> 1;         // output row within tile (0..1)
    int wc   = wid & 1;          // f-half (0..1)
    int lr   = lane & 15;
    int hi   = lane >> 4;        // 0..3

    // ---- async stage: 32 KB contiguous window (rows oh0..oh0+3) -> LDS, linear ----
    {
        const char* src = (const char*)(xsw + ((b * 64 + oh0) * 64) * 64);
        char* dst = (char*)xs;
#pragma unroll
        for (int i = 0; i < 8; ++i) {
            int chunk = (i * 4 + wid) * 1024;    // wave-uniform 1-KB chunk
            gload_lds16(src + chunk + lane * 16, dst + chunk);
        }
    }

    // ---- prologue: W fragments for p=0 into registers ----
    const bf16x8* wg = (const bf16x8*)wq;        // 16-B fragment units
    int fb0 = wc * 64 + lr;                      // + ni*16 -> f row of this lane
    bf16x8 wfrag[2][8];                          // [buf][kh*4+ni], all indices static
#pragma unroll
    for (int kh = 0; kh < 2; ++kh)
#pragma unroll
        for (int ni = 0; ni < 4; ++ni)
            wfrag[0][kh * 4 + ni] = wg[(kh * 128 + fb0 + ni * 16) * 4 + hi];

    f32x4 acc[4][4];                             // [ni: f-block][mi: ow-block]
#pragma unroll
    for (int ni = 0; ni < 4; ++ni)
#pragma unroll
        for (int mi = 0; mi < 4; ++mi) acc[ni][mi] = (f32x4){0.f, 0.f, 0.f, 0.f};

    __syncthreads();                             // drains vmcnt: stage + p0 weights done

#pragma unroll
    for (int p = 0; p < 9; ++p) {
        const int cur = p & 1, nxt = cur ^ 1;
        if (p < 8) {                             // issue next-p weight loads early
#pragma unroll
            for (int kh = 0; kh < 2; ++kh)
#pragma unroll
                for (int ni = 0; ni < 4; ++ni)
                    wfrag[nxt][kh * 4 + ni] = wg[(((p + 1) * 2 + kh) * 128 + fb0 + ni * 16) * 4 + hi];
        }
        const int ki = p / 3, kj = p % 3;
#pragma unroll
        for (int kb = 0; kb < 2; ++kb) {
            int c0 = kb * 32 + hi * 8;
            bf16x8 af[4];
#pragma unroll
            for (int mi = 0; mi < 4; ++mi) {
                int col  = mi * 16 + lr + kj;    // ow + kj, <= 65
                int colc = col > 63 ? 63 : col;  // clamped cols only feed masked ow>=62
                af[mi] = *(const bf16x8*)(&xs[(((wr + ki) * 64 + colc) << 6) + (c0 ^ ((colc & 7) << 3))]);
            }
#pragma unroll
            for (int ni = 0; ni < 4; ++ni)
#pragma unroll
                for (int mi = 0; mi < 4; ++mi)   // A = weights (m=f), B = x (n=ow)
                    acc[ni][mi] = __builtin_amdgcn_mfma_f32_16x16x32_bf16(
                        wfrag[cur][kb * 4 + ni], af[mi], acc[ni][mi], 0, 0, 0);
        }
    }

    // ---- epilogue: D row = f = hi*4+t, col = ow = lr -> coalesced over ow ----
    int oh = oh0 + wr;
    float* ob = out + b * (128 * 62 * 62);
#pragma unroll
    for (int ni = 0; ni < 4; ++ni) {
        int fb = wc * 64 + ni * 16 + (hi << 2);
        f32x4 bv4 = *(const f32x4*)(bias + fb);
#pragma unroll
        for (int t = 0; t < 4; ++t) {
            float* orow = ob + ((fb + t) * 62 + oh) * 62;
#pragma unroll
            for (int mi = 0; mi < 4; ++mi) {
                int ow = mi * 16 + lr;
                if (ow < 62) orow[ow] = acc[ni][mi][t] + bv4[t];
            }
        }
    }
}

extern "C" void kernel_launch(void* const* d_in, const int* in_sizes, int n_in,
                              void* d_out, int out_size, void* d_ws, size_t ws_size,
                              hipStream_t stream) {
    const float* x    = (const float*)d_in[0];
    const float* k1   = (const float*)d_in[1];
    const float* k2   = (const float*)d_in[2];
    const float* bias = (const float*)d_in[3];
    float* out = (float*)d_out;

    unsigned short* wq  = (unsigned short*)d_ws;             // 147456 B
    unsigned short* xsw = (unsigned short*)d_ws + 73728;     // 16.78 MB

    hipLaunchKernelGGL(wprep_kernel, dim3(288), dim3(256), 0, stream, k1, k2, wq);
    hipLaunchKernelGGL(xprep_kernel, dim3(2048), dim3(256), 0, stream, x, xsw);
    hipLaunchKernelGGL(conv_kernel, dim3(992), dim3(256), 0, stream, x /*unused*/ == nullptr ? xsw : xsw, wq, bias, out);
}

// Round 5
// 118.296 us; speedup vs baseline: 1.1525x; 1.1525x over previous
//
#include <hip/hip_runtime.h>
#include <hip/hip_bf16.h>

typedef __attribute__((ext_vector_type(4))) float f32x4;
typedef __attribute__((ext_vector_type(8))) short bf16x8;

static __device__ __forceinline__ unsigned int f2bf(float f) {
    unsigned int u = __float_as_uint(f);
    return (u + 0x7FFFu + ((u >> 16) & 1u)) >> 16;   // RNE
}

static __device__ __forceinline__ void gload_lds16(const void* g, void* l) {
    __builtin_amdgcn_global_load_lds(
        (const __attribute__((address_space(1))) unsigned int*)g,
        (__attribute__((address_space(3))) unsigned int*)l, 16, 0, 0);
}

// ---- prep 1: W -> swizzled LDS image, wq[p] = 8192 shorts ready for linear copy ----
// short offset within p-chunk: f*64 + ((cc*8) ^ ((f&7)<<3)), granule = 8 channels.
__global__ __launch_bounds__(256) void wprep_kernel(const float* __restrict__ k1,
                                                    const float* __restrict__ k2,
                                                    unsigned short* __restrict__ wq) {
    int g = blockIdx.x * 256 + threadIdx.x;            // 9*128*8 = 9216 granules
    if (g >= 9216) return;
    int cc = g & 7;
    int f  = (g >> 3) & 127;
    int p  = g >> 10;
    unsigned int w[4];
#pragma unroll
    for (int e2 = 0; e2 < 4; ++e2) {
        int s0 = (p * 64 + cc * 8 + e2 * 2) * 128 + f; // k1/k2 are (p, c, f)
        unsigned int lo = f2bf(expf(k1[s0]) - expf(k2[s0]));
        int s1 = s0 + 128;
        unsigned int hh = f2bf(expf(k1[s1]) - expf(k2[s1]));
        w[e2] = lo | (hh << 16);
    }
    *(uint4*)(wq + p * 8192 + f * 64 + ((cc * 8) ^ ((f & 7) << 3))) =
        *(const uint4*)w;
}

// ---- prep 2: x NCHW f32 -> PRE-SWIZZLED NHWC bf16 (granule j holds c-block (j&7)^(col&7)) ----
__global__ __launch_bounds__(256) void xprep_kernel(const float* __restrict__ x,
                                                    unsigned short* __restrict__ xsw) {
    __shared__ float t[64][65];
    int b = blockIdx.x >> 6;
    int h = blockIdx.x & 63;
    const float* xb = x + b * 262144 + h * 64;         // + c*4096 + col
    int tid = threadIdx.x;
    int col4 = (tid & 15) * 4;
    int c0   = tid >> 4;
#pragma unroll
    for (int i = 0; i < 4; ++i) {
        int c = c0 + i * 16;
        f32x4 v = *(const f32x4*)(xb + c * 4096 + col4);
        t[c][col4 + 0] = v[0]; t[c][col4 + 1] = v[1];
        t[c][col4 + 2] = v[2]; t[c][col4 + 3] = v[3];
    }
    __syncthreads();
    unsigned short* orow = xsw + ((size_t)(b * 64 + h)) * 4096;
#pragma unroll
    for (int i = 0; i < 2; ++i) {
        int j   = tid + i * 256;                       // granule 0..511
        int col = j >> 3;
        int cb  = ((j & 7) ^ (col & 7)) * 8;
        uint4 pk;
        pk.x = f2bf(t[cb + 0][col]) | (f2bf(t[cb + 1][col]) << 16);
        pk.y = f2bf(t[cb + 2][col]) | (f2bf(t[cb + 3][col]) << 16);
        pk.z = f2bf(t[cb + 4][col]) | (f2bf(t[cb + 5][col]) << 16);
        pk.w = f2bf(t[cb + 6][col]) | (f2bf(t[cb + 7][col]) << 16);
        *(uint4*)(orow + j * 8) = pk;
    }
}

// ---- main: implicit-GEMM conv, all global traffic via global_load_lds ----
// Per block: 1 image x 4 output rows. M=128 F, N=256 (4 oh x 64 ow-pad), K=576.
// Weights: LDS double-buffer, staged per-p, raw barrier + explicit vmcnt (no drain).
__global__ __launch_bounds__(256, 2) void conv_kernel(const unsigned short* __restrict__ xsw,
                                                      const unsigned short* __restrict__ wq,
                                                      const float* __restrict__ bias,
                                                      float* __restrict__ out) {
    __shared__ unsigned short xs[6 * 64 * 64];     // 48 KB: rows oh0..oh0+5 (clamped)
    __shared__ unsigned short bs[2][128 * 64];     // 2 x 16 KB weight buffers

    int bid0 = blockIdx.x;                         // 512 = 8 * 64
    int bid  = (bid0 & 7) * 64 + (bid0 >> 3);      // XCD-chunked swizzle (bijective)
    int b    = bid >> 4;
    int tile = bid & 15;
    int oh0  = tile * 4;                           // output rows oh0..oh0+3

    int tid  = threadIdx.x;
    int lane = tid & 63;
    int wid  = tid >> 6;
    int wr   = wid >> 1;       // oh-pair (0..1)
    int wc   = wid & 1;        // f-half (0..1)
    int lr   = lane & 15;
    int hi   = lane >> 4;      // 0..3

    // ---- prologue stage: xs (48 chunks of 1 KB) + bs[0] (16 chunks), fire-and-forget ----
    {
        const unsigned short* srcb = xsw + (size_t)b * 262144;
#pragma unroll
        for (int i = 0; i < 12; ++i) {
            int chunk = i * 4 + wid;               // 0..47, wave-uniform dst
            int row   = chunk >> 3;                // 0..5
            int srow  = oh0 + row; if (srow > 63) srow = 63;   // clamp: feeds masked oh
            gload_lds16((const char*)(srcb + srow * 4096) + (chunk & 7) * 1024 + lane * 16,
                        (char*)xs + chunk * 1024);
        }
#pragma unroll
        for (int i = 0; i < 4; ++i) {
            int chunk = i * 4 + wid;               // 0..15
            gload_lds16((const char*)wq + chunk * 1024 + lane * 16,
                        (char*)bs[0] + chunk * 1024);
        }
    }

    f32x4 acc[4][8];                               // [ni: f-block][oh2*4 + mi]
#pragma unroll
    for (int ni = 0; ni < 4; ++ni)
#pragma unroll
        for (int q = 0; q < 8; ++q) acc[ni][q] = (f32x4){0.f, 0.f, 0.f, 0.f};

#pragma unroll
    for (int p = 0; p < 9; ++p) {
        asm volatile("s_waitcnt vmcnt(0)" ::: "memory");   // waited loads are 1 iter old
        __builtin_amdgcn_s_barrier();                      // raw: no compiler drain
        __builtin_amdgcn_sched_barrier(0);
        if (p < 8) {                               // stage bs[nxt]: issue-and-forget
#pragma unroll
            for (int i = 0; i < 4; ++i) {
                int chunk = i * 4 + wid;
                gload_lds16((const char*)wq + (p + 1) * 16384 + chunk * 1024 + lane * 16,
                            (char*)bs[(p + 1) & 1] + chunk * 1024);
            }
        }
        const int ki = p / 3, kj = p % 3;
        const unsigned short* bc = bs[p & 1];
#pragma unroll
        for (int kb = 0; kb < 2; ++kb) {
            int c0 = kb * 32 + hi * 8;
            bf16x8 bfr[4];
#pragma unroll
            for (int ni = 0; ni < 4; ++ni) {
                int f = wc * 64 + ni * 16 + lr;
                bfr[ni] = *(const bf16x8*)(&bc[f * 64 + (c0 ^ ((f & 7) << 3))]);
            }
#pragma unroll
            for (int oh2 = 0; oh2 < 2; ++oh2) {
                int row = wr * 2 + oh2 + ki;       // 0..5
#pragma unroll
                for (int mi = 0; mi < 4; ++mi) {
                    int col  = mi * 16 + lr + kj;  // <= 65
                    int colc = col > 63 ? 63 : col;
                    bf16x8 af = *(const bf16x8*)(&xs[((row * 64 + colc) << 6) + (c0 ^ ((colc & 7) << 3))]);
#pragma unroll
                    for (int ni = 0; ni < 4; ++ni)
                        acc[ni][oh2 * 4 + mi] = __builtin_amdgcn_mfma_f32_16x16x32_bf16(
                            bfr[ni], af, acc[ni][oh2 * 4 + mi], 0, 0, 0);
                }
            }
        }
    }

    // ---- epilogue: D row = f = hi*4+t, col = ow = lr -> coalesced over ow ----
    float* ob = out + b * 492032;                  // 128*62*62
#pragma unroll
    for (int ni = 0; ni < 4; ++ni) {
        int fb = wc * 64 + ni * 16 + (hi << 2);
        f32x4 bv4 = *(const f32x4*)(bias + fb);
#pragma unroll
        for (int t = 0; t < 4; ++t) {
#pragma unroll
            for (int oh2 = 0; oh2 < 2; ++oh2) {
                int oh = oh0 + wr * 2 + oh2;
                if (oh < 62) {
                    float* orow = ob + ((fb + t) * 62 + oh) * 62;
#pragma unroll
                    for (int mi = 0; mi < 4; ++mi) {
                        int ow = mi * 16 + lr;
                        if (ow < 62) orow[ow] = acc[ni][oh2 * 4 + mi][t] + bv4[t];
                    }
                }
            }
        }
    }
}

extern "C" void kernel_launch(void* const* d_in, const int* in_sizes, int n_in,
                              void* d_out, int out_size, void* d_ws, size_t ws_size,
                              hipStream_t stream) {
    const float* x    = (const float*)d_in[0];
    const float* k1   = (const float*)d_in[1];
    const float* k2   = (const float*)d_in[2];
    const float* bias = (const float*)d_in[3];
    float* out = (float*)d_out;

    unsigned short* wq  = (unsigned short*)d_ws;             // 9*8192 = 147456 B
    unsigned short* xsw = (unsigned short*)d_ws + 73728;     // 16.78 MB

    hipLaunchKernelGGL(wprep_kernel, dim3(36), dim3(256), 0, stream, k1, k2, wq);
    hipLaunchKernelGGL(xprep_kernel, dim3(2048), dim3(256), 0, stream, x, xsw);
    hipLaunchKernelGGL(conv_kernel, dim3(512), dim3(256), 0, stream, xsw, wq, bias, out);
}

// Round 6
// 114.798 us; speedup vs baseline: 1.1876x; 1.0305x over previous
//
#include <hip/hip_runtime.h>
#include <hip/hip_bf16.h>

typedef __attribute__((ext_vector_type(4))) float f32x4;
typedef __attribute__((ext_vector_type(8))) short bf16x8;

static __device__ __forceinline__ unsigned int f2bf(float f) {
    unsigned int u = __float_as_uint(f);
    return (u + 0x7FFFu + ((u >> 16) & 1u)) >> 16;   // RNE
}

static __device__ __forceinline__ void gload_lds16(const void* g, void* l) {
    __builtin_amdgcn_global_load_lds(
        (const __attribute__((address_space(1))) unsigned int*)g,
        (__attribute__((address_space(3))) unsigned int*)l, 16, 0, 0);
}

// ---- merged prep ----
// blocks 0..2047:  x NCHW f32 -> PRE-SWIZZLED NHWC bf16 (granule j holds c-block (j&7)^(col&7))
// blocks 2048..2083: W fragment-ordered wq[p][kb][f][ch32] = bf16(exp(k1)-exp(k2))
__global__ __launch_bounds__(256) void prep_kernel(const float* __restrict__ x,
                                                   const float* __restrict__ k1,
                                                   const float* __restrict__ k2,
                                                   unsigned short* __restrict__ xsw,
                                                   unsigned short* __restrict__ wq) {
    __shared__ float t[64][65];
    int blk = blockIdx.x;
    int tid = threadIdx.x;
    if (blk >= 2048) {                                 // ---- weight prep ----
        int g = (blk - 2048) * 256 + tid;              // 9*2*128*4 = 9216 granules
        if (g >= 9216) return;
        int ch8 = g & 3;
        int f   = (g >> 2) & 127;
        int kb  = (g >> 9) & 1;
        int p   = g >> 10;
        unsigned int w[4];
#pragma unroll
        for (int e2 = 0; e2 < 4; ++e2) {
            int c  = kb * 32 + ch8 * 8 + e2 * 2;
            int s0 = (p * 64 + c) * 128 + f;           // k1/k2 are (p, c, f)
            unsigned int lo = f2bf(expf(k1[s0]) - expf(k2[s0]));
            unsigned int hh = f2bf(expf(k1[s0 + 128]) - expf(k2[s0 + 128]));
            w[e2] = lo | (hh << 16);
        }
        *(uint4*)(wq + ((p * 2 + kb) * 128 + f) * 32 + ch8 * 8) = *(const uint4*)w;
        return;
    }
    // ---- x prep ----
    int b = blk >> 6;
    int h = blk & 63;
    const float* xb = x + b * 262144 + h * 64;         // + c*4096 + col
    int col4 = (tid & 15) * 4;
    int c0   = tid >> 4;
#pragma unroll
    for (int i = 0; i < 4; ++i) {
        int c = c0 + i * 16;
        f32x4 v = *(const f32x4*)(xb + c * 4096 + col4);
        t[c][col4 + 0] = v[0]; t[c][col4 + 1] = v[1];
        t[c][col4 + 2] = v[2]; t[c][col4 + 3] = v[3];
    }
    __syncthreads();
    unsigned short* orow = xsw + ((size_t)(b * 64 + h)) * 4096;
#pragma unroll
    for (int i = 0; i < 2; ++i) {
        int j   = tid + i * 256;                       // granule 0..511
        int col = j >> 3;
        int cb  = ((j & 7) ^ (col & 7)) * 8;
        uint4 pk;
        pk.x = f2bf(t[cb + 0][col]) | (f2bf(t[cb + 1][col]) << 16);
        pk.y = f2bf(t[cb + 2][col]) | (f2bf(t[cb + 3][col]) << 16);
        pk.z = f2bf(t[cb + 4][col]) | (f2bf(t[cb + 5][col]) << 16);
        pk.w = f2bf(t[cb + 6][col]) | (f2bf(t[cb + 7][col]) << 16);
        *(uint4*)(orow + j * 8) = pk;
    }
}

// ---- main: implicit-GEMM conv. x: linear global_load_lds of pre-swizzled rows.
// Weights: register double-buffer via inline-asm loads (compiler cannot sink them).
// ONE barrier total; waves free-run through all 9 positions.
__global__ __launch_bounds__(256, 2) void conv_kernel(const unsigned short* __restrict__ xsw,
                                                      const unsigned short* __restrict__ wq,
                                                      const float* __restrict__ bias,
                                                      float* __restrict__ out) {
    __shared__ unsigned short xs[6 * 64 * 64];     // 48 KB: rows oh0..oh0+5 (clamped)

    int bid0 = blockIdx.x;                         // 512 = 8 * 64
    int bid  = (bid0 & 7) * 64 + (bid0 >> 3);      // XCD-chunked swizzle (bijective)
    int b    = bid >> 4;
    int tile = bid & 15;
    int oh0  = tile * 4;                           // output rows oh0..oh0+3

    int tid  = threadIdx.x;
    int lane = tid & 63;
    int wid  = tid >> 6;
    int wr   = wid >> 1;       // oh-pair (0..1)
    int wc   = wid & 1;        // f-half (0..1)
    int lr   = lane & 15;
    int hi   = lane >> 4;      // 0..3

    // ---- stage xs: 48 x 1 KB chunks, fire-and-forget ----
    {
        const unsigned short* srcb = xsw + (size_t)b * 262144;
#pragma unroll
        for (int i = 0; i < 12; ++i) {
            int chunk = i * 4 + wid;               // 0..47, wave-uniform dst
            int row   = chunk >> 3;                // 0..5
            int srow  = oh0 + row; if (srow > 63) srow = 63;   // clamp: feeds masked oh
            gload_lds16((const char*)(srcb + srow * 4096) + (chunk & 7) * 1024 + lane * 16,
                        (char*)xs + chunk * 1024);
        }
    }

    // ---- weight register double-buffer; lane base covers (f=wc*64+lr, c=hi*8..) ----
    const unsigned short* wl = wq + (wc * 64 + lr) * 32 + hi * 8;
    bf16x8 wfrag[2][8];                            // [buf][kb*4+ni], all static indices
#pragma unroll
    for (int kb = 0; kb < 2; ++kb)
#pragma unroll
        for (int ni = 0; ni < 4; ++ni)
            asm volatile("global_load_dwordx4 %0, %1, off"
                         : "=&v"(wfrag[0][kb * 4 + ni])
                         : "v"(wl + kb * 4096 + ni * 512) : "memory");

    f32x4 acc[4][8];                               // [ni: f-block][oh2*4 + mi]
#pragma unroll
    for (int ni = 0; ni < 4; ++ni)
#pragma unroll
        for (int q = 0; q < 8; ++q) acc[ni][q] = (f32x4){0.f, 0.f, 0.f, 0.f};

    asm volatile("s_waitcnt vmcnt(0)" ::: "memory");   // xs + wfrag[0] landed
    __builtin_amdgcn_s_barrier();                      // xs visible to all waves
    __builtin_amdgcn_sched_barrier(0);

#pragma unroll
    for (int p = 0; p < 9; ++p) {
        const int cur = p & 1, nxt = cur ^ 1;
        if (p > 0) {                               // wait wfrag[cur] (issued at p-1)
            asm volatile("s_waitcnt vmcnt(0)" ::: "memory");
            __builtin_amdgcn_sched_barrier(0);
        }
        if (p < 8) {                               // issue next-p loads (cannot be sunk)
#pragma unroll
            for (int kb = 0; kb < 2; ++kb)
#pragma unroll
                for (int ni = 0; ni < 4; ++ni)
                    asm volatile("global_load_dwordx4 %0, %1, off"
                                 : "=&v"(wfrag[nxt][kb * 4 + ni])
                                 : "v"(wl + (p + 1) * 8192 + kb * 4096 + ni * 512) : "memory");
        }
        const int ki = p / 3, kj = p % 3;
#pragma unroll
        for (int kb = 0; kb < 2; ++kb) {
            int c0 = kb * 32 + hi * 8;
#pragma unroll
            for (int oh2 = 0; oh2 < 2; ++oh2) {
                int row = wr * 2 + oh2 + ki;       // 0..5
#pragma unroll
                for (int mi = 0; mi < 4; ++mi) {
                    int col  = mi * 16 + lr + kj;  // <= 65
                    int colc = col > 63 ? 63 : col;
                    bf16x8 af = *(const bf16x8*)(&xs[((row * 64 + colc) << 6) + (c0 ^ ((colc & 7) << 3))]);
#pragma unroll
                    for (int ni = 0; ni < 4; ++ni)
                        acc[ni][oh2 * 4 + mi] = __builtin_amdgcn_mfma_f32_16x16x32_bf16(
                            wfrag[cur][kb * 4 + ni], af, acc[ni][oh2 * 4 + mi], 0, 0, 0);
                }
            }
        }
    }

    // ---- epilogue: D row = f = hi*4+t, col = ow = lr -> coalesced over ow ----
    float* ob = out + b * 492032;                  // 128*62*62
#pragma unroll
    for (int ni = 0; ni < 4; ++ni) {
        int fb = wc * 64 + ni * 16 + (hi << 2);
        f32x4 bv4 = *(const f32x4*)(bias + fb);
#pragma unroll
        for (int t = 0; t < 4; ++t) {
#pragma unroll
            for (int oh2 = 0; oh2 < 2; ++oh2) {
                int oh = oh0 + wr * 2 + oh2;
                if (oh < 62) {
                    float* orow = ob + ((fb + t) * 62 + oh) * 62;
#pragma unroll
                    for (int mi = 0; mi < 4; ++mi) {
                        int ow = mi * 16 + lr;
                        if (ow < 62) orow[ow] = acc[ni][oh2 * 4 + mi][t] + bv4[t];
                    }
                }
            }
        }
    }
}

extern "C" void kernel_launch(void* const* d_in, const int* in_sizes, int n_in,
                              void* d_out, int out_size, void* d_ws, size_t ws_size,
                              hipStream_t stream) {
    const float* x    = (const float*)d_in[0];
    const float* k1   = (const float*)d_in[1];
    const float* k2   = (const float*)d_in[2];
    const float* bias = (const float*)d_in[3];
    float* out = (float*)d_out;

    unsigned short* wq  = (unsigned short*)d_ws;             // 73728 shorts = 147456 B
    unsigned short* xsw = (unsigned short*)d_ws + 73728;     // 16.78 MB

    hipLaunchKernelGGL(prep_kernel, dim3(2084), dim3(256), 0, stream, x, k1, k2, xsw, wq);
    hipLaunchKernelGGL(conv_kernel, dim3(512), dim3(256), 0, stream, xsw, wq, bias, out);
}